// Round 5
// baseline (1552.547 us; speedup 1.0000x reference)
//
#include <hip/hip_runtime.h>

// Problem: n_obs=2048, n_x=64, n_y=256, N_ITERS=200, all fp32.
// d_out[0:524288) = z_star, d_out[524288:1048576) = y_hat.

#define NOBS 2048
#define NY   256
#define NX   64
#define NIT  200

#define PROWS 112                                   // Sigma rows persistent in LDS
#define FISTA_LDS ((PROWS + 32 + 8) * NY * 4)       // Sp + red + wb = 155648 B
#define POWER_LDS (256*264*2 + 256*4 + 256*4)       // 137216 B

__device__ __forceinline__ float rlane(float v, int l) {
  return __int_as_float(__builtin_amdgcn_readlane(__float_as_int(v), l));
}

// ---------------------------------------------------------------- zero
__global__ void zero_kernel(float* cs, float* tr) {
  cs[threadIdx.x] = 0.0f;
  if (threadIdx.x < 5) tr[threadIdx.x] = 0.0f;
}

// ---------------------------------------------------------------- y_hat / ep / colsum
__global__ __launch_bounds__(256) void yhat_kernel(
    const float* __restrict__ x, const float* __restrict__ y,
    const float* __restrict__ W, const float* __restrict__ bias,
    float* __restrict__ yh, float* __restrict__ ep,
    float* __restrict__ colsum, float* __restrict__ yh_out)
{
  __shared__ float xs[8 * NX];
  const int tid = threadIdx.x;
  const int r0  = blockIdx.x * 8;
  xs[tid]       = x[r0 * NX + tid];
  xs[tid + 256] = x[r0 * NX + tid + 256];
  float wr[NX];
  #pragma unroll
  for (int q = 0; q < NX / 4; ++q)
    *(float4*)&wr[q * 4] = *(const float4*)&W[tid * NX + q * 4];
  const float bj = bias[tid];
  __syncthreads();
  float esum = 0.0f;
  #pragma unroll 1
  for (int r = 0; r < 8; ++r) {
    float acc = bj;
    #pragma unroll
    for (int k = 0; k < NX; ++k) acc += xs[r * NX + k] * wr[k];
    const int gi = (r0 + r) * NY + tid;
    yh[gi] = acc;
    yh_out[gi] = acc;
    const float e = y[gi] - acc;
    ep[gi] = e;
    esum += e;
  }
  atomicAdd(&colsum[tid], esum);
}

// ---------------------------------------------------------------- C = M^T M (+post-ops)
// sigma mode (colsum!=0): C = MtM*invn - mu mu^T, mu=colsum*invn.
// square mode: C = (M/D)^2 with D = scale_src[0] (M symmetric, NY columns).
// trace_out (if set) accumulates trace of the FINAL (scaled) C — used to
// re-normalize every squaring so (Sigma-power) entries never underflow f32.
__global__ __launch_bounds__(256) void ata_kernel(
    const float* __restrict__ M, int K, float* __restrict__ C,
    const float* __restrict__ colsum, const float* __restrict__ scale_src,
    float* __restrict__ trace_out, float invn)
{
  __shared__ float Ea[32][33], Eb[32][33];
  const int bi = blockIdx.x >> 3, bj = blockIdx.x & 7;
  const int i0 = bi * 32, j0 = bj * 32;
  const int tid = threadIdx.x, tx = tid & 15, ty = tid >> 4;
  float a00 = 0, a01 = 0, a10 = 0, a11 = 0;
  for (int k0 = 0; k0 < K; k0 += 32) {
    #pragma unroll
    for (int s = 0; s < 4; ++s) {
      int e = tid + 256 * s, t = e >> 5, c = e & 31;
      Ea[t][c] = M[(k0 + t) * NY + i0 + c];
      Eb[t][c] = M[(k0 + t) * NY + j0 + c];
    }
    __syncthreads();
    #pragma unroll
    for (int t = 0; t < 32; ++t) {
      float av0 = Ea[t][ty * 2], av1 = Ea[t][ty * 2 + 1];
      float bv0 = Eb[t][tx * 2], bv1 = Eb[t][tx * 2 + 1];
      a00 += av0 * bv0; a01 += av0 * bv1;
      a10 += av1 * bv0; a11 += av1 * bv1;
    }
    __syncthreads();
  }
  float scl = 1.0f;
  if (scale_src) { float D = scale_src[0]; scl = 1.0f / (D * D); }
  const int gi0 = i0 + ty * 2, gj0 = j0 + tx * 2;
  float vals[4] = {a00, a01, a10, a11};
  #pragma unroll
  for (int a = 0; a < 2; ++a) {
    #pragma unroll
    for (int b2 = 0; b2 < 2; ++b2) {
      float v = vals[a * 2 + b2];
      int gi = gi0 + a, gj = gj0 + b2;
      if (colsum) v = v * invn - (colsum[gi] * invn) * (colsum[gj] * invn);
      else        v *= scl;
      C[gi * NY + gj] = v;
      if (trace_out && gi == gj) atomicAdd(trace_out, v);
    }
  }
}

// ---------------------------------------------------------------- power iteration + Rayleigh
// B16 proportional to Sigma^16 (trace-renormalized at each squaring, so entries
// are always in f32/bf16 range). 26 power iters on bf16 LDS copy, then Rayleigh
// quotient u'Sig u/u'u in f32. Rayleigh <= lam_max always; x1.001 inflation
// guarantees step <= 1/L (FISTA condition) with margin over the power-iteration
// residual; at iter 200 the fixed point is step-insensitive at this scale.
__global__ __launch_bounds__(256) void power_kernel(
    const float* __restrict__ B16, const float* __restrict__ Sig,
    float* __restrict__ step_out)
{
  extern __shared__ char smc[];
  unsigned short* Bb = (unsigned short*)smc;          // [256][264] bf16
  float* u   = (float*)(smc + 256 * 264 * 2);
  float* red = u + 256;
  const int j = threadIdx.x;
  for (int k = 0; k < 256; ++k) {
    unsigned int bits = __float_as_uint(B16[k * NY + j]);
    unsigned int r = (bits + 0x7FFFu + ((bits >> 16) & 1u)) >> 16;  // RNE
    Bb[k * 264 + j] = (unsigned short)r;   // symmetric: row j == col j
  }
  u[j] = 1.0f + 0.001f * (float)j;
  __syncthreads();
  for (int it = 0; it < 26; ++it) {
    float acc = 0.0f;
    const unsigned short* row = Bb + j * 264;
    #pragma unroll 4
    for (int k = 0; k < 256; k += 8) {
      uint4 pk = *(const uint4*)(row + k);
      float4 ua = *(const float4*)&u[k];
      float4 ub = *(const float4*)&u[k + 4];
      acc += __uint_as_float((pk.x & 0xffffu) << 16) * ua.x;
      acc += __uint_as_float( pk.x & 0xffff0000u    ) * ua.y;
      acc += __uint_as_float((pk.y & 0xffffu) << 16) * ua.z;
      acc += __uint_as_float( pk.y & 0xffff0000u    ) * ua.w;
      acc += __uint_as_float((pk.z & 0xffffu) << 16) * ub.x;
      acc += __uint_as_float( pk.z & 0xffff0000u    ) * ub.y;
      acc += __uint_as_float((pk.w & 0xffffu) << 16) * ub.z;
      acc += __uint_as_float( pk.w & 0xffff0000u    ) * ub.w;
    }
    red[j] = fabsf(acc);
    __syncthreads();
    for (int s = 128; s > 0; s >>= 1) {
      if (j < s) red[j] = fmaxf(red[j], red[j + s]);
      __syncthreads();
    }
    float mx = red[0];
    __syncthreads();
    u[j] = acc / mx;
    __syncthreads();
  }
  float wv = 0.0f;
  for (int k = 0; k < 256; ++k) wv += Sig[k * NY + j] * u[k];
  red[j] = wv * u[j];
  __syncthreads();
  for (int s = 128; s > 0; s >>= 1) { if (j < s) red[j] += red[j + s]; __syncthreads(); }
  float num = red[0];
  __syncthreads();
  red[j] = u[j] * u[j];
  __syncthreads();
  for (int s = 128; s > 0; s >>= 1) { if (j < s) red[j] += red[j + s]; __syncthreads(); }
  if (j == 0) {
    float lam = (num / red[0]) * 1.001f;
    step_out[0] = 1.0f / (lam + 1e-8f);
  }
}

// ---------------------------------------------------------------- FISTA
__device__ __forceinline__ float wsum64(float v) {
  #pragma unroll
  for (int m = 1; m < 64; m <<= 1) v += __shfl_xor(v, m, 64);
  return v;
}

// Exact simplex projection threshold (Michelot), one row per wave.
// Active set shrinks every non-final pass -> terminates in <= 256 passes;
// break-on-stable makes the high cap cost-free in the typical ~5-15 passes.
__device__ __forceinline__ float proj1(const float v[4]) {
  float sum = wsum64(v[0] + v[1] + v[2] + v[3]);
  int c = 256;
  float th = (sum - 1.0f) * (1.0f / 256.0f);
  #pragma unroll 1
  for (int pass = 0; pass < 300; ++pass) {
    float p = (v[0] > th ? v[0] : 0.0f) + (v[1] > th ? v[1] : 0.0f)
            + (v[2] > th ? v[2] : 0.0f) + (v[3] > th ? v[3] : 0.0f);
    int n = __popcll(__ballot(v[0] > th)) + __popcll(__ballot(v[1] > th))
          + __popcll(__ballot(v[2] > th)) + __popcll(__ballot(v[3] > th));
    if (n == c) break;                     // active set stable -> theta final
    float sm = wsum64(p);
    th = (sm - 1.0f) / (float)n;
    c = n;
  }
  return th;
}

// one 4-row k-group for 4 obs-rows: acc[t][q] += sum_j w[t][k_j]*S[k_j][c0+q]
// (w broadcast via readlane -> SGPR operand of v_fmac: zero VGPR cost)
__device__ __forceinline__ void mv_group4(const float wk[4], int g,
                                          float4 s0, float4 s1, float4 s2, float4 s3,
                                          float acc[4][4]) {
  #pragma unroll
  for (int t = 0; t < 4; ++t) {
    float w0 = rlane(wk[t], 4*g + 0), w1 = rlane(wk[t], 4*g + 1);
    float w2 = rlane(wk[t], 4*g + 2), w3 = rlane(wk[t], 4*g + 3);
    acc[t][0] += w0*s0.x; acc[t][1] += w0*s0.y; acc[t][2] += w0*s0.z; acc[t][3] += w0*s0.w;
    acc[t][0] += w1*s1.x; acc[t][1] += w1*s1.y; acc[t][2] += w1*s1.z; acc[t][3] += w1*s1.w;
    acc[t][0] += w2*s2.x; acc[t][1] += w2*s2.y; acc[t][2] += w2*s2.z; acc[t][3] += w2*s2.w;
    acc[t][0] += w3*s3.x; acc[t][1] += w3*s3.y; acc[t][2] += w3*s3.z; acc[t][3] += w3*s3.w;
  }
}

// 512-thread / 8-wave FISTA, 2 teams x 4 waves (2 waves/SIMD for TLP).
// Team tm (waves 4tm..4tm+3) handles obs-rows 4tm..4tm+3 of the block's 8.
// Within a team, wave u owns Sigma rows k in {16g+4u+j}. Sigma is
// iteration-invariant: rows k<PROWS live in LDS (shared by both teams);
// the remaining 36 rows/wave live in REGISTERS (float4 sreg[36], all indices
// compile-time) -> the 200-iteration loop issues ZERO global loads.
// Partial gradients reduce through 32KB LDS; each wave owns one obs-row for
// projection/momentum. 2 barriers per iteration.
__global__ __launch_bounds__(512, 2) void fista_kernel(
    const float* __restrict__ Sig, const float* __restrict__ yh,
    const float* __restrict__ step_ptr, float* __restrict__ zout)
{
  extern __shared__ float lds[];
  float* Sp  = lds;                       // [112][256] persistent Sigma rows
  float* red = lds + PROWS * NY;          // [2][4][4][256] partial gradients
  float* wb  = red + 32 * NY;             // [8][256] w rows (k-gather source)

  const int tid = threadIdx.x;
  const int wv = tid >> 6, ln = tid & 63;
  const int tm = wv >> 2;                 // team 0/1
  const int u  = wv & 3;                  // k-split index within team
  const int c0 = ln << 2;                 // 4 owned columns
  const int rowl = tm * 4 + u;            // owned obs-row within block (0..7)
  const int gR = (blockIdx.x * 8 + rowl) * NY;
  const int kml = (ln >> 2) * 16 + u * 4 + (ln & 3);   // k owned by this lane in wk[]

  // stage persistent Sigma rows [0, PROWS): 7168 float4s / 512 threads = 14 each
  #pragma unroll 1
  for (int q = 0; q < 14; ++q) {
    int f = (q * 512 + tid) * 4;
    *(float4*)&Sp[f] = *(const float4*)&Sig[f];
  }

  // register-resident Sigma rows [PROWS, 256): groups g=7..15, rows 16g+4u+j
  float4 sreg[36];
  #pragma unroll
  for (int g = 0; g < 9; ++g) {
    const float* gp = Sig + (16 * (g + 7) + 4 * u) * NY + c0;
    sreg[g * 4 + 0] = *(const float4*)(gp);
    sreg[g * 4 + 1] = *(const float4*)(gp + NY);
    sreg[g * 4 + 2] = *(const float4*)(gp + 2 * NY);
    sreg[g * 4 + 3] = *(const float4*)(gp + 3 * NY);
  }

  const float step = step_ptr[0];
  float yhR[4];
  { float4 t4 = *(const float4*)&yh[gR + c0]; yhR[0]=t4.x; yhR[1]=t4.y; yhR[2]=t4.z; yhR[3]=t4.w; }

  const float z0v = 1.0f / 256.0f;
  float zR[4] = {z0v,z0v,z0v,z0v};
  float wR[4] = {z0v,z0v,z0v,z0v};
  float wk[4] = {z0v,z0v,z0v,z0v};        // w[team row t][kml]; uniform at t=0
  float tmom = 1.0f;
  __syncthreads();                        // Sp staged

  for (int it = 0; it < NIT; ++it) {
    float acc[4][4];
    #pragma unroll
    for (int t = 0; t < 4; ++t) {
      acc[t][0] = 0.0f; acc[t][1] = 0.0f; acc[t][2] = 0.0f; acc[t][3] = 0.0f;
    }

    // persistent groups g=0..6 (rows 16g+4u+j from LDS)
    #pragma unroll
    for (int g = 0; g < 7; ++g) {
      const float* sp = Sp + (16 * g + 4 * u) * NY + c0;
      float4 s0 = *(const float4*)(sp);
      float4 s1 = *(const float4*)(sp + NY);
      float4 s2 = *(const float4*)(sp + 2 * NY);
      float4 s3 = *(const float4*)(sp + 3 * NY);
      mv_group4(wk, g, s0, s1, s2, s3, acc);
    }

    // register-resident groups g=7..15 (zero memory traffic)
    #pragma unroll
    for (int g = 7; g < 16; ++g) {
      mv_group4(wk, g, sreg[(g - 7) * 4 + 0], sreg[(g - 7) * 4 + 1],
                sreg[(g - 7) * 4 + 2], sreg[(g - 7) * 4 + 3], acc);
    }

    // publish partials: red[tm][u][t][c]
    #pragma unroll
    for (int t = 0; t < 4; ++t)
      *(float4*)&red[((tm * 4 + u) * 4 + t) * NY + c0] =
          make_float4(acc[t][0], acc[t][1], acc[t][2], acc[t][3]);
    __syncthreads();                      // barrier 1

    // reduce own row (t = u) across the team's 4 waves
    float4 p0 = *(const float4*)&red[((tm * 4 + 0) * 4 + u) * NY + c0];
    float4 p1 = *(const float4*)&red[((tm * 4 + 1) * 4 + u) * NY + c0];
    float4 p2 = *(const float4*)&red[((tm * 4 + 2) * 4 + u) * NY + c0];
    float4 p3 = *(const float4*)&red[((tm * 4 + 3) * 4 + u) * NY + c0];
    float g0 = p0.x + p1.x + p2.x + p3.x, g1 = p0.y + p1.y + p2.y + p3.y;
    float g2 = p0.z + p1.z + p2.z + p3.z, g3 = p0.w + p1.w + p2.w + p3.w;

    // v = w - step*(g - yhat)
    float vR[4];
    vR[0] = wR[0] - step * (g0 - yhR[0]);
    vR[1] = wR[1] - step * (g1 - yhR[1]);
    vR[2] = wR[2] - step * (g2 - yhR[2]);
    vR[3] = wR[3] - step * (g3 - yhR[3]);

    const float th = proj1(vR);

    const float tn = 0.5f * (1.0f + sqrtf(1.0f + 4.0f * tmom * tmom));
    const float coef = (tmom - 1.0f) / tn;
    tmom = tn;
    #pragma unroll
    for (int q = 0; q < 4; ++q) {
      float zn = fmaxf(vR[q] - th, 0.0f);
      wR[q] = zn + coef * (zn - zR[q]);
      zR[q] = zn;
    }
    *(float4*)&wb[rowl * NY + c0] = make_float4(wR[0], wR[1], wR[2], wR[3]);
    __syncthreads();                      // barrier 2: w published

    #pragma unroll
    for (int t = 0; t < 4; ++t) wk[t] = wb[(tm * 4 + t) * NY + kml];  // k-gather
  }

  *(float4*)&zout[gR + c0] = make_float4(zR[0], zR[1], zR[2], zR[3]);
}

// ---------------------------------------------------------------- launch
extern "C" void kernel_launch(void* const* d_in, const int* in_sizes, int n_in,
                              void* d_out, int out_size, void* d_ws, size_t ws_size,
                              hipStream_t stream) {
  const float* x = (const float*)d_in[0];
  const float* y = (const float*)d_in[1];
  const float* W = (const float*)d_in[2];
  const float* b = (const float*)d_in[3];
  float* out = (float*)d_out;
  float* ws  = (float*)d_ws;

  float* ep  = ws;                  // 524288
  float* yh  = ws + 524288;         // 524288
  float* Sg  = ws + 1048576;        // 65536
  float* Bb0 = ws + 1114112;        // 65536
  float* Bb1 = ws + 1179648;        // 65536
  float* cs  = ws + 1245184;        // 256
  float* tr  = ws + 1245440;        // 5 trace slots (per-squaring renorm)
  float* stp = ws + 1245445;        // 1

  zero_kernel<<<1, 256, 0, stream>>>(cs, tr);
  yhat_kernel<<<NOBS / 8, 256, 0, stream>>>(x, y, W, b, yh, ep, cs, out + 524288);
  // Sigma = ep'ep/n - mu mu', trace -> tr[0]
  ata_kernel<<<64, 256, 0, stream>>>(ep, NOBS, Sg, cs, nullptr, &tr[0], 1.0f / (float)NOBS);
  // Trace-renormalized repeated squaring (Sigma symmetric -> M^T M = M^2):
  // each stage computes (prev/trace_prev)^2 and records its own trace, keeping
  // lam_max of every intermediate in [1/256, 1] -> no f32/bf16 underflow.
  ata_kernel<<<64, 256, 0, stream>>>(Sg,  NY, Bb0, nullptr, &tr[0], &tr[1], 0.0f);
  ata_kernel<<<64, 256, 0, stream>>>(Bb0, NY, Bb1, nullptr, &tr[1], &tr[2], 0.0f);
  ata_kernel<<<64, 256, 0, stream>>>(Bb1, NY, Bb0, nullptr, &tr[2], &tr[3], 0.0f);
  ata_kernel<<<64, 256, 0, stream>>>(Bb0, NY, Bb1, nullptr, &tr[3], nullptr, 0.0f);

  hipFuncSetAttribute((const void*)power_kernel,
                      hipFuncAttributeMaxDynamicSharedMemorySize, POWER_LDS);
  power_kernel<<<1, 256, POWER_LDS, stream>>>(Bb1, Sg, stp);

  hipFuncSetAttribute((const void*)fista_kernel,
                      hipFuncAttributeMaxDynamicSharedMemorySize, FISTA_LDS);
  fista_kernel<<<NOBS / 8, 512, FISTA_LDS, stream>>>(Sg, yh, stp, out);
}

// Round 6
// 1180.431 us; speedup vs baseline: 1.3152x; 1.3152x over previous
//
#include <hip/hip_runtime.h>

// Problem: n_obs=2048, n_x=64, n_y=256, N_ITERS=200, all fp32.
// d_out[0:524288) = z_star, d_out[524288:1048576) = y_hat.

#define NOBS 2048
#define NY   256
#define NX   64
#define NIT  200

// fista LDS layout (bytes)
#define SHI_OFF  0          // [256][264] ushort  = 135168
#define WHI_OFF  135168     // [16][264]  ushort  = 8448
#define WLO_OFF  143616     // [16][264]  ushort  = 8448
#define GBUF_OFF 152064     // [8][260]   float   = 8320
#define FISTA_LDS 160384    // <= 163840
#define POWER_LDS (256*264*2 + 256*4 + 256*4)   // 137216

typedef __attribute__((ext_vector_type(8))) short short8v;   // 8 bf16 (4 VGPR)
typedef __attribute__((ext_vector_type(4))) float f32x4;

__device__ __forceinline__ unsigned short f2bf(float f) {    // RNE f32->bf16
  unsigned int b = __float_as_uint(f);
  return (unsigned short)((b + 0x7FFFu + ((b >> 16) & 1u)) >> 16);
}
__device__ __forceinline__ float bf2f(unsigned short h) {
  return __uint_as_float(((unsigned int)h) << 16);
}

// ---------------------------------------------------------------- zero
__global__ void zero_kernel(float* cs, float* tr) {
  cs[threadIdx.x] = 0.0f;
  if (threadIdx.x < 5) tr[threadIdx.x] = 0.0f;
}

// ---------------------------------------------------------------- y_hat / ep / colsum
__global__ __launch_bounds__(256) void yhat_kernel(
    const float* __restrict__ x, const float* __restrict__ y,
    const float* __restrict__ W, const float* __restrict__ bias,
    float* __restrict__ yh, float* __restrict__ ep,
    float* __restrict__ colsum, float* __restrict__ yh_out)
{
  __shared__ float xs[8 * NX];
  const int tid = threadIdx.x;
  const int r0  = blockIdx.x * 8;
  xs[tid]       = x[r0 * NX + tid];
  xs[tid + 256] = x[r0 * NX + tid + 256];
  float wr[NX];
  #pragma unroll
  for (int q = 0; q < NX / 4; ++q)
    *(float4*)&wr[q * 4] = *(const float4*)&W[tid * NX + q * 4];
  const float bj = bias[tid];
  __syncthreads();
  float esum = 0.0f;
  #pragma unroll 1
  for (int r = 0; r < 8; ++r) {
    float acc = bj;
    #pragma unroll
    for (int k = 0; k < NX; ++k) acc += xs[r * NX + k] * wr[k];
    const int gi = (r0 + r) * NY + tid;
    yh[gi] = acc;
    yh_out[gi] = acc;
    const float e = y[gi] - acc;
    ep[gi] = e;
    esum += e;
  }
  atomicAdd(&colsum[tid], esum);
}

// ---------------------------------------------------------------- C = M^T M (+post-ops)
// sigma mode (colsum!=0): C = MtM*invn - mu mu^T, mu=colsum*invn.
// square mode: C = (M/D)^2 with D = scale_src[0] (M symmetric, NY columns).
// trace_out accumulates trace of the FINAL scaled C (per-squaring renorm).
__global__ __launch_bounds__(256) void ata_kernel(
    const float* __restrict__ M, int K, float* __restrict__ C,
    const float* __restrict__ colsum, const float* __restrict__ scale_src,
    float* __restrict__ trace_out, float invn)
{
  __shared__ float Ea[32][33], Eb[32][33];
  const int bi = blockIdx.x >> 3, bj = blockIdx.x & 7;
  const int i0 = bi * 32, j0 = bj * 32;
  const int tid = threadIdx.x, tx = tid & 15, ty = tid >> 4;
  float a00 = 0, a01 = 0, a10 = 0, a11 = 0;
  for (int k0 = 0; k0 < K; k0 += 32) {
    #pragma unroll
    for (int s = 0; s < 4; ++s) {
      int e = tid + 256 * s, t = e >> 5, c = e & 31;
      Ea[t][c] = M[(k0 + t) * NY + i0 + c];
      Eb[t][c] = M[(k0 + t) * NY + j0 + c];
    }
    __syncthreads();
    #pragma unroll
    for (int t = 0; t < 32; ++t) {
      float av0 = Ea[t][ty * 2], av1 = Ea[t][ty * 2 + 1];
      float bv0 = Eb[t][tx * 2], bv1 = Eb[t][tx * 2 + 1];
      a00 += av0 * bv0; a01 += av0 * bv1;
      a10 += av1 * bv0; a11 += av1 * bv1;
    }
    __syncthreads();
  }
  float scl = 1.0f;
  if (scale_src) { float D = scale_src[0]; scl = 1.0f / (D * D); }
  const int gi0 = i0 + ty * 2, gj0 = j0 + tx * 2;
  float vals[4] = {a00, a01, a10, a11};
  #pragma unroll
  for (int a = 0; a < 2; ++a) {
    #pragma unroll
    for (int b2 = 0; b2 < 2; ++b2) {
      float v = vals[a * 2 + b2];
      int gi = gi0 + a, gj = gj0 + b2;
      if (colsum) v = v * invn - (colsum[gi] * invn) * (colsum[gj] * invn);
      else        v *= scl;
      C[gi * NY + gj] = v;
      if (trace_out && gi == gj) atomicAdd(trace_out, v);
    }
  }
}

// ---------------------------------------------------------------- power iteration + Rayleigh
__global__ __launch_bounds__(256) void power_kernel(
    const float* __restrict__ B16, const float* __restrict__ Sig,
    float* __restrict__ step_out)
{
  extern __shared__ char smc[];
  unsigned short* Bb = (unsigned short*)smc;          // [256][264] bf16
  float* u   = (float*)(smc + 256 * 264 * 2);
  float* red = u + 256;
  const int j = threadIdx.x;
  for (int k = 0; k < 256; ++k) {
    Bb[k * 264 + j] = f2bf(B16[k * NY + j]);   // symmetric: row j == col j
  }
  u[j] = 1.0f + 0.001f * (float)j;
  __syncthreads();
  for (int it = 0; it < 26; ++it) {
    float acc = 0.0f;
    const unsigned short* row = Bb + j * 264;
    #pragma unroll 4
    for (int k = 0; k < 256; k += 8) {
      uint4 pk = *(const uint4*)(row + k);
      float4 ua = *(const float4*)&u[k];
      float4 ub = *(const float4*)&u[k + 4];
      acc += __uint_as_float((pk.x & 0xffffu) << 16) * ua.x;
      acc += __uint_as_float( pk.x & 0xffff0000u    ) * ua.y;
      acc += __uint_as_float((pk.y & 0xffffu) << 16) * ua.z;
      acc += __uint_as_float( pk.y & 0xffff0000u    ) * ua.w;
      acc += __uint_as_float((pk.z & 0xffffu) << 16) * ub.x;
      acc += __uint_as_float( pk.z & 0xffff0000u    ) * ub.y;
      acc += __uint_as_float((pk.w & 0xffffu) << 16) * ub.z;
      acc += __uint_as_float( pk.w & 0xffff0000u    ) * ub.w;
    }
    red[j] = fabsf(acc);
    __syncthreads();
    for (int s = 128; s > 0; s >>= 1) {
      if (j < s) red[j] = fmaxf(red[j], red[j + s]);
      __syncthreads();
    }
    float mx = red[0];
    __syncthreads();
    u[j] = acc / mx;
    __syncthreads();
  }
  float wv = 0.0f;
  for (int k = 0; k < 256; ++k) wv += Sig[k * NY + j] * u[k];
  red[j] = wv * u[j];
  __syncthreads();
  for (int s = 128; s > 0; s >>= 1) { if (j < s) red[j] += red[j + s]; __syncthreads(); }
  float num = red[0];
  __syncthreads();
  red[j] = u[j] * u[j];
  __syncthreads();
  for (int s = 128; s > 0; s >>= 1) { if (j < s) red[j] += red[j + s]; __syncthreads(); }
  if (j == 0) {
    float lam = (num / red[0]) * 1.001f;
    step_out[0] = 1.0f / (lam + 1e-8f);
  }
}

// ---------------------------------------------------------------- FISTA
__device__ __forceinline__ float wsum64(float v) {
  #pragma unroll
  for (int m = 1; m < 64; m <<= 1) v += __shfl_xor(v, m, 64);
  return v;
}

// Exact simplex projection threshold (Michelot), one row per wave.
__device__ __forceinline__ float proj1(const float v[4]) {
  float sum = wsum64(v[0] + v[1] + v[2] + v[3]);
  int c = 256;
  float th = (sum - 1.0f) * (1.0f / 256.0f);
  #pragma unroll 1
  for (int pass = 0; pass < 300; ++pass) {
    float p = (v[0] > th ? v[0] : 0.0f) + (v[1] > th ? v[1] : 0.0f)
            + (v[2] > th ? v[2] : 0.0f) + (v[3] > th ? v[3] : 0.0f);
    int n = __popcll(__ballot(v[0] > th)) + __popcll(__ballot(v[1] > th))
          + __popcll(__ballot(v[2] > th)) + __popcll(__ballot(v[3] > th));
    if (n == c) break;                     // active set stable -> theta final
    float sm = wsum64(p);
    th = (sm - 1.0f) / (float)n;
    c = n;
  }
  return th;
}

// MFMA FISTA: per block 8 obs-rows padded to M=16. g = w @ Sigma via
// mfma_f32_16x16x32_bf16 with split precision:
//   g ~= A_hi B_hi + A_lo B_hi + A_hi B_lo   (dropped A_lo B_lo ~ 2^-18)
// B_hi = bf16(Sigma) in LDS [256][264] (padded -> 2-way-free fragment reads,
// symmetric so B[k][n] read as row n0+lane%16); B_lo = registers (16 frags/wave,
// iteration-invariant). A = w rows in LDS bf16 hi/lo [16][264], rows 8..15 = 0.
// Wave w owns n-tiles {2w,2w+1} for MFMA and obs-row w for proj/momentum.
// Fragment maps: A[m][k]: m=lane%16, k=8*(lane/16)+e (K-contiguous per lane);
// B[k][n]: n=lane%16, k=8*(lane/16)+e; C/D: col=lane&15, row=(lane>>4)*4+reg
// (C/D verified layout). 2 barriers/iter.
__global__ __launch_bounds__(512, 2) void fista_kernel(
    const float* __restrict__ Sig, const float* __restrict__ yh,
    const float* __restrict__ step_ptr, float* __restrict__ zout)
{
  extern __shared__ char smem[];
  unsigned short* Shi = (unsigned short*)(smem + SHI_OFF);
  unsigned short* Whi = (unsigned short*)(smem + WHI_OFF);
  unsigned short* Wlo = (unsigned short*)(smem + WLO_OFF);
  float* gbuf = (float*)(smem + GBUF_OFF);

  const int tid = threadIdx.x;
  const int w = tid >> 6, ln = tid & 63;
  const int lm = ln & 15, lg = ln >> 4;

  // ---- stage Shi = bf16(Sigma): thread -> row tid>>1, half tid&1
  {
    const int r = tid >> 1, h = tid & 1;
    const float* src = Sig + r * NY + h * 128;
    unsigned short* dst = Shi + r * 264 + h * 128;
    #pragma unroll
    for (int j = 0; j < 16; ++j) {
      float4 f0 = *(const float4*)(src + j * 8);
      float4 f1 = *(const float4*)(src + j * 8 + 4);
      short8v v;
      v[0] = (short)f2bf(f0.x); v[1] = (short)f2bf(f0.y);
      v[2] = (short)f2bf(f0.z); v[3] = (short)f2bf(f0.w);
      v[4] = (short)f2bf(f1.x); v[5] = (short)f2bf(f1.y);
      v[6] = (short)f2bf(f1.z); v[7] = (short)f2bf(f1.w);
      *(short8v*)(dst + j * 8) = v;
    }
  }
  // zero pad rows 8..15 of Whi/Wlo (cols 0..255)
  for (int j = tid; j < 8 * 256; j += 512) {
    int r = 8 + (j >> 8), c = j & 255;
    Whi[r * 264 + c] = 0; Wlo[r * 264 + c] = 0;
  }

  // ---- Sigma_lo fragments in registers: wave w, n-tiles 2w, 2w+1
  short8v slo[2][8];
  #pragma unroll
  for (int nt = 0; nt < 2; ++nt) {
    const int row = 32 * w + 16 * nt + lm;
    #pragma unroll
    for (int kk = 0; kk < 8; ++kk) {
      const float* gp = Sig + row * NY + kk * 32 + lg * 8;
      float4 f0 = *(const float4*)(gp);
      float4 f1 = *(const float4*)(gp + 4);
      short8v v; float e;
      e = f0.x; v[0] = (short)f2bf(e - bf2f(f2bf(e)));
      e = f0.y; v[1] = (short)f2bf(e - bf2f(f2bf(e)));
      e = f0.z; v[2] = (short)f2bf(e - bf2f(f2bf(e)));
      e = f0.w; v[3] = (short)f2bf(e - bf2f(f2bf(e)));
      e = f1.x; v[4] = (short)f2bf(e - bf2f(f2bf(e)));
      e = f1.y; v[5] = (short)f2bf(e - bf2f(f2bf(e)));
      e = f1.z; v[6] = (short)f2bf(e - bf2f(f2bf(e)));
      e = f1.w; v[7] = (short)f2bf(e - bf2f(f2bf(e)));
      slo[nt][kk] = v;
    }
  }

  const float step = step_ptr[0];
  const int gR = (blockIdx.x * 8 + w) * NY;
  float yhR[4];
  { float4 t4 = *(const float4*)&yh[gR + 4 * ln];
    yhR[0] = t4.x; yhR[1] = t4.y; yhR[2] = t4.z; yhR[3] = t4.w; }

  const float z0v = 1.0f / 256.0f;
  float zR[4] = {z0v, z0v, z0v, z0v};
  float wR[4] = {z0v, z0v, z0v, z0v};
  float tmom = 1.0f;

  // initial w row: hi = 2^-8 (exact), lo = 0
  {
    unsigned short h0 = f2bf(z0v);
    unsigned int p = (unsigned int)h0 | ((unsigned int)h0 << 16);
    *(uint2*)(Whi + w * 264 + ln * 4) = make_uint2(p, p);
    *(uint2*)(Wlo + w * 264 + ln * 4) = make_uint2(0u, 0u);
  }
  __syncthreads();                        // staging + init visible

  const int a_idx  = lm * 264 + lg * 8;                    // + kk*32
  const int b0_idx = (32 * w + lm) * 264 + lg * 8;         // + kk*32
  const int b1_idx = (32 * w + 16 + lm) * 264 + lg * 8;    // + kk*32

  for (int it = 0; it < NIT; ++it) {
    f32x4 acc0 = {0.f, 0.f, 0.f, 0.f};
    f32x4 acc1 = {0.f, 0.f, 0.f, 0.f};
    #pragma unroll
    for (int kk = 0; kk < 8; ++kk) {
      short8v ahi = *(const short8v*)(Whi + a_idx + kk * 32);
      short8v alo = *(const short8v*)(Wlo + a_idx + kk * 32);
      short8v b0  = *(const short8v*)(Shi + b0_idx + kk * 32);
      short8v b1  = *(const short8v*)(Shi + b1_idx + kk * 32);
      acc0 = __builtin_amdgcn_mfma_f32_16x16x32_bf16(ahi, b0, acc0, 0, 0, 0);
      acc1 = __builtin_amdgcn_mfma_f32_16x16x32_bf16(ahi, b1, acc1, 0, 0, 0);
      acc0 = __builtin_amdgcn_mfma_f32_16x16x32_bf16(alo, b0, acc0, 0, 0, 0);
      acc1 = __builtin_amdgcn_mfma_f32_16x16x32_bf16(alo, b1, acc1, 0, 0, 0);
      acc0 = __builtin_amdgcn_mfma_f32_16x16x32_bf16(ahi, slo[0][kk], acc0, 0, 0, 0);
      acc1 = __builtin_amdgcn_mfma_f32_16x16x32_bf16(ahi, slo[1][kk], acc1, 0, 0, 0);
    }
    // scatter gradient rows (real rows 0..7 live in lanes 0..31); conflict-free
    if (ln < 32) {
      const int rb = lg * 4;
      #pragma unroll
      for (int r = 0; r < 4; ++r) {
        gbuf[(rb + r) * 260 + 32 * w + lm]      = acc0[r];
        gbuf[(rb + r) * 260 + 32 * w + 16 + lm] = acc1[r];
      }
    }
    __syncthreads();                      // barrier 1: gradients ready

    float4 g4 = *(const float4*)&gbuf[w * 260 + 4 * ln];
    float vR[4];
    vR[0] = wR[0] - step * (g4.x - yhR[0]);
    vR[1] = wR[1] - step * (g4.y - yhR[1]);
    vR[2] = wR[2] - step * (g4.z - yhR[2]);
    vR[3] = wR[3] - step * (g4.w - yhR[3]);

    const float th = proj1(vR);

    const float tn = 0.5f * (1.0f + sqrtf(1.0f + 4.0f * tmom * tmom));
    const float coef = (tmom - 1.0f) / tn;
    tmom = tn;
    #pragma unroll
    for (int q = 0; q < 4; ++q) {
      float zn = fmaxf(vR[q] - th, 0.0f);
      wR[q] = zn + coef * (zn - zR[q]);
      zR[q] = zn;
    }
    // publish new w row as bf16 hi/lo
    unsigned short h0 = f2bf(wR[0]), h1 = f2bf(wR[1]);
    unsigned short h2 = f2bf(wR[2]), h3 = f2bf(wR[3]);
    unsigned short l0 = f2bf(wR[0] - bf2f(h0)), l1 = f2bf(wR[1] - bf2f(h1));
    unsigned short l2 = f2bf(wR[2] - bf2f(h2)), l3 = f2bf(wR[3] - bf2f(h3));
    *(uint2*)(Whi + w * 264 + ln * 4) =
        make_uint2((unsigned)h0 | ((unsigned)h1 << 16),
                   (unsigned)h2 | ((unsigned)h3 << 16));
    *(uint2*)(Wlo + w * 264 + ln * 4) =
        make_uint2((unsigned)l0 | ((unsigned)l1 << 16),
                   (unsigned)l2 | ((unsigned)l3 << 16));
    __syncthreads();                      // barrier 2: w published
  }

  *(float4*)&zout[gR + 4 * ln] = make_float4(zR[0], zR[1], zR[2], zR[3]);
}

// ---------------------------------------------------------------- launch
extern "C" void kernel_launch(void* const* d_in, const int* in_sizes, int n_in,
                              void* d_out, int out_size, void* d_ws, size_t ws_size,
                              hipStream_t stream) {
  const float* x = (const float*)d_in[0];
  const float* y = (const float*)d_in[1];
  const float* W = (const float*)d_in[2];
  const float* b = (const float*)d_in[3];
  float* out = (float*)d_out;
  float* ws  = (float*)d_ws;

  float* ep  = ws;                  // 524288
  float* yh  = ws + 524288;         // 524288
  float* Sg  = ws + 1048576;        // 65536
  float* Bb0 = ws + 1114112;        // 65536
  float* Bb1 = ws + 1179648;        // 65536
  float* cs  = ws + 1245184;        // 256
  float* tr  = ws + 1245440;        // 5 trace slots (per-squaring renorm)
  float* stp = ws + 1245445;        // 1

  zero_kernel<<<1, 256, 0, stream>>>(cs, tr);
  yhat_kernel<<<NOBS / 8, 256, 0, stream>>>(x, y, W, b, yh, ep, cs, out + 524288);
  // Sigma = ep'ep/n - mu mu', trace -> tr[0]
  ata_kernel<<<64, 256, 0, stream>>>(ep, NOBS, Sg, cs, nullptr, &tr[0], 1.0f / (float)NOBS);
  // Trace-renormalized repeated squaring (Sigma symmetric -> M^T M = M^2)
  ata_kernel<<<64, 256, 0, stream>>>(Sg,  NY, Bb0, nullptr, &tr[0], &tr[1], 0.0f);
  ata_kernel<<<64, 256, 0, stream>>>(Bb0, NY, Bb1, nullptr, &tr[1], &tr[2], 0.0f);
  ata_kernel<<<64, 256, 0, stream>>>(Bb1, NY, Bb0, nullptr, &tr[2], &tr[3], 0.0f);
  ata_kernel<<<64, 256, 0, stream>>>(Bb0, NY, Bb1, nullptr, &tr[3], nullptr, 0.0f);

  hipFuncSetAttribute((const void*)power_kernel,
                      hipFuncAttributeMaxDynamicSharedMemorySize, POWER_LDS);
  power_kernel<<<1, 256, POWER_LDS, stream>>>(Bb1, Sg, stp);

  hipFuncSetAttribute((const void*)fista_kernel,
                      hipFuncAttributeMaxDynamicSharedMemorySize, FISTA_LDS);
  fista_kernel<<<NOBS / 8, 512, FISTA_LDS, stream>>>(Sg, yh, stp, out);
}